// Round 10
// baseline (884.570 us; speedup 1.0000x reference)
//
#include <hip/hip_runtime.h>

// 2-layer LSTM, B=2048, T=4096, IN=1, H=8, OUT=1, fp32.
//
// R17 = R15 VERBATIM + one-time wave desync only. (R16 bundled desync
// with float4 x-loads; the x-loads were misaligned -- steady chunks sit
// at xp+5+4ck, offset 1 mod 4 floats -- and corrupted x. Reverted. The
// desync itself is timing-only and cannot change numerics.)
//
// Model (R8..R15): wall 505cy/iter = 424cy VALU busy (84%, 2 waves/SIMD)
// + ~80cy joint-stall bubble. Hypothesis: co-resident waves run in
// lockstep, so their chain-stall windows align; a one-time phase offset
// (s_sleep 0..3 x ~64cy keyed on blockIdx^waveid) decorrelates them and
// lets one wave's issue fill the other's bubble.
// Ledger: v_pk_fma_f32 is HALF-RATE on gfx950 (157.3 TF spec == scalar
// fma peak) -- packed fp32 closed. Misaligned float4 x-load closed.
//
// Structure (R15, proven): 1 seq/wave64, lane = L*32 + j*4 + g.
// Spare-dot DS ship double-buffered across bodies: body(m) issues
// swz16(am2); body(m+1) forms d2 = an2_hold + s2p at its top, stores,
// ships via bperm (full-body slack). s1 ships via permlane16_swap
// (on-chain, VALU). Gates pre-scaled by -log2e; cs = c*N2L2E fold.
// Fills 0,1,2 zero L1; bodies 3,4 no store; steady m = 5..Tsz+4,
// store op[m-5].

constexpr int Bsz = 2048;
constexpr int Tsz = 4096;

typedef int v2i __attribute__((ext_vector_type(2)));

template <int CTRL>
__device__ __forceinline__ float dpp(float v) {
    return __int_as_float(
        __builtin_amdgcn_mov_dpp(__float_as_int(v), CTRL, 0xF, 0xF, true));
}
// quad_perm bcast0..3 = 0x00,0x55,0xAA,0xFF; quad xor3 = 0x1B;
// row_half_mirror (xor7) = 0x141; row_mirror (xor15) = 0x140

// v[lane^16] via V_PERMLANE16_SWAP_B32 (VALU; verified bit-exact in R11).
__device__ __forceinline__ float xchg16(float v, bool hi16) {
    const int vi = __float_as_int(v);
    v2i p = __builtin_amdgcn_permlane16_swap(vi, vi, false, false);
    return __int_as_float(hi16 ? p.x : p.y);
}

__device__ __forceinline__ float swz16(float v) {
    // ds_swizzle bit mode, xor 0x10 within each 32-lane group
    return __int_as_float(
        __builtin_amdgcn_ds_swizzle(__float_as_int(v), (16 << 10) | 0x1f));
}

__device__ __forceinline__ float bperm(int addr, float v) {
    return __int_as_float(__builtin_amdgcn_ds_bpermute(addr, __float_as_int(v)));
}

__global__ void __launch_bounds__(256, 2) lstm2_ds2(
    const float* __restrict__ x,      // [B, T]
    const float* __restrict__ Wih0,   // [32, 1]
    const float* __restrict__ Whh0,   // [32, 8]
    const float* __restrict__ bih0,   // [32]
    const float* __restrict__ bhh0,   // [32]
    const float* __restrict__ Wih1,   // [32, 8]
    const float* __restrict__ Whh1,   // [32, 8]
    const float* __restrict__ bih1,   // [32]
    const float* __restrict__ bhh1,   // [32]
    const float* __restrict__ Wlin,   // [1, 8]
    const float* __restrict__ blin,   // [1]
    float* __restrict__ out)          // [B, T]
{
    const int tid  = threadIdx.x;
    const int lane = tid & 63;
    const int g    = lane & 3;
    const int j    = (lane >> 2) & 7;
    const int L    = (lane >> 5) & 1;
    const int wv   = tid >> 6;
    const int seq  = blockIdx.x * 4 + wv;

    const int jm = j ^ 4;             // mirror lane's unit
    const int r  = g * 8 + j;         // own gate row
    const int rm = g * 8 + jm;        // mirror lane's gate row

    const bool hi16 = (lane & 16) != 0;

    const float NL2E  = -1.4426950408889634f;
    const float N2L2E = -2.8853900817779268f;
    const bool  isG   = (g == 2);
    const float ws    = isG ? N2L2E : NL2E;
    // c-scale fold: g~ lanes produce tanh(g)*N2L2E directly
    const float sA    = isG ? 2.0f * N2L2E : 1.0f;
    const float oA    = isG ? -N2L2E : 0.0f;

    const float* __restrict__ Whh = L ? Whh1 : Whh0;
    const float* __restrict__ bih = L ? bih1 : bih0;
    const float* __restrict__ bhh = L ? bhh1 : bhh0;

    // near weights (own row) + mirror-row weights, k = j^i for i=0..3
    float wn1[4], wm1[4], wn2[4], wm2[4];
#pragma unroll
    for (int i = 0; i < 4; ++i) {
        const int k = j ^ i;
        wn1[i] = Whh[r * 8 + k] * ws;
        wm1[i] = Whh[rm * 8 + k] * ws;
        wn2[i] = L ? Wlin[k] : Wih1[r * 8 + k] * ws;
        wm2[i] = L ? Wlin[k] : Wih1[rm * 8 + k] * ws;
    }
    const float bias = (bih[r] + bhh[r]) * ws;
    const float wx   = L ? 0.0f : Wih0[r] * ws;
    const float b2   = L ? blin[0] : 0.0f;
    const float mL   = L ? 1.0f : 0.0f;
    const float keep = 1.0f - mL;
    const int  xaddr = (lane ^ 32) * 4;   // bpermute: cross layer halves

    const float* __restrict__ xp = x + (size_t)seq * Tsz;
    float* __restrict__ op       = out + (size_t)seq * Tsz;
    const bool storeLane = (lane == 32);

    float hn0 = 0.0f, hn1 = 0.0f, hn2 = 0.0f, hn3 = 0.0f;
    float cs = 0.0f;          // c' = c * N2L2E (scale-folded cell state)
    float recvP = 0.0f;       // bperm result in flight (1-body slack)
    float an2_hold = 0.0f;    // near spare dot from previous body
    float s2p = 0.0f;         // swz16 result in flight (1-body slack)

    auto body = [&](float xt, bool fill, float* storePtr) {
        // ---- top: consume previous body's in-flight DS results
        const float d2 = an2_hold + s2p;   // = full spare dot of h(m-2)
        if (storePtr && storeLane) *storePtr = d2;   // proj -> op[m-5]
        const float rB = recvP;            // bperm(d2(m-1)) result
        recvP = bperm(xaddr, d2);          // issue; consumed next body
        const float t0 = fmaf(mL, rB, fmaf(wx, xt, bias));

        // -- mirror partials from entering hn (= h(m-1))
        float am2 = wm2[0] * hn0;
        am2 = fmaf(wm2[1], hn1, am2);
        am2 = fmaf(wm2[2], hn2, am2);
        am2 = fmaf(wm2[3], hn3, am2);
        s2p = swz16(am2);                  // issue; consumed next body

        float am1 = wm1[0] * hn0;
        am1 = fmaf(wm1[1], hn1, am1);
        am1 = fmaf(wm1[2], hn2, am1);
        am1 = fmaf(wm1[3], hn3, am1);
        const float s1 = xchg16(am1, hi16);   // ON-CHAIN: VALU permlane swap

        // -- near dots
        float an1 = fmaf(wn1[0], hn0, t0);
        an1 = fmaf(wn1[1], hn1, an1);
        an1 = fmaf(wn1[2], hn2, an1);
        an1 = fmaf(wn1[3], hn3, an1);
        float an2 = fmaf(wn2[0], hn0, b2);
        an2 = fmaf(wn2[1], hn1, an2);
        an2 = fmaf(wn2[2], hn2, an2);
        an2 = fmaf(wn2[3], hn3, an2);
        an2_hold = an2;

        // -- z: near (incl. recvB via t0) + far(ship)
        const float z = an1 + s1;

        // -- activation (pre-scaled): sig, or tanh*N2L2E for g~ lanes
        float a = fmaf(sA,
                       __builtin_amdgcn_rcpf(1.0f + __builtin_amdgcn_exp2f(z)),
                       oA);
        const float gi = dpp<0x00>(a);
        const float gf = dpp<0x55>(a);
        const float gG = dpp<0xAA>(a);        // = tanh(g)*N2L2E (pre-scaled)
        const float go = dpp<0xFF>(a);
        const float go2 = go + go;            // off-critical
        cs = fmaf(gf, cs, gi * gG);           // c' = c*N2L2E
        const float e  = __builtin_amdgcn_exp2f(cs);
        const float rr = __builtin_amdgcn_rcpf(1.0f + e);
        float h = fmaf(go2, rr, -go);         // = go*(2*rr-1)

        if (fill) { h *= keep; cs *= keep; }  // keep L1 state at zero

        // -- near-h gather for next iter (intra-row DPP only)
        const float m7  = dpp<0x141>(h);     // ^7
        const float m15 = dpp<0x140>(h);     // ^15
        hn0 = h;                             // j
        hn1 = dpp<0x1B>(m7);                 // ^7^3  = ^4  -> j^1
        hn2 = dpp<0x141>(m15);               // ^15^7 = ^8  -> j^2
        hn3 = dpp<0x1B>(m15);                // ^15^3 = ^12 -> j^3
    };

    // ---- prologue: bodies 0,1,2 zero L1 state; 3,4 run free, no store
    body(xp[0], true, nullptr);
    body(xp[1], true, nullptr);
    body(xp[2], true, nullptr);
    body(xp[3], false, nullptr);
    body(xp[4], false, nullptr);

    // ---- one-time wave desync: stagger co-resident waves' phases so
    // chain-stall windows decorrelate (phase 0..3 x ~64cy). Timing-only.
    {
        const int phase = (blockIdx.x ^ wv) & 3;
        if (phase & 1) __builtin_amdgcn_s_sleep(1);
        if (phase & 2) __builtin_amdgcn_s_sleep(2);
    }

    // ---- steady, unrolled x4: m = 5 .. Tsz+4, store op[m-5]
    float xc[4];
#pragma unroll
    for (int u = 0; u < 4; ++u) xc[u] = xp[5 + u];   // x(5..8), Tsz >> 9
    for (int ck = 0; ck < Tsz / 4; ++ck) {
        const int base = 5 + 4 * ck;
        float xf[4];
#pragma unroll
        for (int u = 0; u < 4; ++u) {
            int idx = base + 4 + u;
            idx = (idx < Tsz) ? idx : (Tsz - 1);
            xf[u] = xp[idx];                 // prefetch next chunk (clamped)
        }
#pragma unroll
        for (int u = 0; u < 4; ++u)
            body(xc[u], false, op + (4 * ck + u));   // op[m-5]
#pragma unroll
        for (int u = 0; u < 4; ++u) xc[u] = xf[u];
    }
}

extern "C" void kernel_launch(void* const* d_in, const int* in_sizes, int n_in,
                              void* d_out, int out_size, void* d_ws, size_t ws_size,
                              hipStream_t stream) {
    const float* x    = (const float*)d_in[0];
    const float* Wih0 = (const float*)d_in[1];
    const float* Whh0 = (const float*)d_in[2];
    const float* bih0 = (const float*)d_in[3];
    const float* bhh0 = (const float*)d_in[4];
    const float* Wih1 = (const float*)d_in[5];
    const float* Whh1 = (const float*)d_in[6];
    const float* bih1 = (const float*)d_in[7];
    const float* bhh1 = (const float*)d_in[8];
    const float* Wlin = (const float*)d_in[9];
    const float* blin = (const float*)d_in[10];
    float* out = (float*)d_out;

    dim3 grid(Bsz / 4);   // 4 waves/block, 1 seq/wave -> 512 blocks, 2048 waves
    dim3 block(256);
    hipLaunchKernelGGL(lstm2_ds2, grid, block, 0, stream,
                       x, Wih0, Whh0, bih0, bhh0,
                       Wih1, Whh1, bih1, bhh1, Wlin, blin, out);
}

// Round 12
// 875.375 us; speedup vs baseline: 1.0105x; 1.0105x over previous
//
#include <hip/hip_runtime.h>

// 2-layer LSTM, B=2048, T=4096, IN=1, H=8, OUT=1, fp32.
//
// R19 = "full-local dots" restructure. R18 failed on a phase mismatch
// (an2 from h(m-1) + s2 from h(m)). Root fix: stop shipping far DOT
// PARTIALS; ship the far H-VALUES once per body instead. Tail of
// body(m): after gathering hn0..3 (= h(m) units j..j^3), issue
// hf_i = swz16(hn_i) (= h(m) units j^4..j^7; lane^16 holds j^4).
// Body(m+1) computes full 8-term dots locally:
//   z  = (t0 + 4 near-fma) + (4-term far dot)     [R15 grouping/order
//   d2 = (b2 + 4 near-fma) + (4-term far dot)      => bit-identical]
// Removes: both mirror dots (8 insts), permlane pair on the z chain,
// s1p/s2p/an2_hold state. Adds: 4 swz16 at tail (~50-60cy cover into
// next body's far dots).
// Pipeline: d2(m) = spare-dot(h(m-1)) formed in-body; bperm ships d2,
// consumed next body (rB(m) = Wih1.h1(m-2); L1 runs 2 behind; store
// d2's L1 half = proj(h2(m-3)) -> op[m-3]). Fills: bodies 0,1 zero L1;
// body 2 = first L1 step, no store; steady m = 3..Tsz+2.
// Closed ledger: packed fp32 (half-rate), all-VALU ships (R11), wave
// desync (R17), misaligned float4 x-loads (R16), R18 phase bug.
//
// Layout: 1 seq/wave64, lane = L*32 + j*4 + g (g=gate i,f,g~,o; j=unit;
// L=layer). 2048 waves = 2 waves/SIMD. Gates pre-scaled by -log2e
// (g~ rows -2log2e): act = rcp(1+exp2(z)); cs = c*N2L2E fold.

constexpr int Bsz = 2048;
constexpr int Tsz = 4096;

template <int CTRL>
__device__ __forceinline__ float dpp(float v) {
    return __int_as_float(
        __builtin_amdgcn_mov_dpp(__float_as_int(v), CTRL, 0xF, 0xF, true));
}
// quad_perm bcast0..3 = 0x00,0x55,0xAA,0xFF; quad xor3 = 0x1B;
// row_half_mirror (xor7) = 0x141; row_mirror (xor15) = 0x140

__device__ __forceinline__ float swz16(float v) {
    // ds_swizzle bit mode, xor 0x10 within each 32-lane group
    return __int_as_float(
        __builtin_amdgcn_ds_swizzle(__float_as_int(v), (16 << 10) | 0x1f));
}

__device__ __forceinline__ float bperm(int addr, float v) {
    return __int_as_float(__builtin_amdgcn_ds_bpermute(addr, __float_as_int(v)));
}

__global__ void __launch_bounds__(256, 2) lstm2_fl(
    const float* __restrict__ x,      // [B, T]
    const float* __restrict__ Wih0,   // [32, 1]
    const float* __restrict__ Whh0,   // [32, 8]
    const float* __restrict__ bih0,   // [32]
    const float* __restrict__ bhh0,   // [32]
    const float* __restrict__ Wih1,   // [32, 8]
    const float* __restrict__ Whh1,   // [32, 8]
    const float* __restrict__ bih1,   // [32]
    const float* __restrict__ bhh1,   // [32]
    const float* __restrict__ Wlin,   // [1, 8]
    const float* __restrict__ blin,   // [1]
    float* __restrict__ out)          // [B, T]
{
    const int tid  = threadIdx.x;
    const int lane = tid & 63;
    const int g    = lane & 3;
    const int j    = (lane >> 2) & 7;
    const int L    = (lane >> 5) & 1;
    const int seq  = blockIdx.x * 4 + (tid >> 6);

    const int r = g * 8 + j;          // own gate row

    const float NL2E  = -1.4426950408889634f;
    const float N2L2E = -2.8853900817779268f;
    const bool  isG   = (g == 2);
    const float ws    = isG ? N2L2E : NL2E;
    // c-scale fold: g~ lanes produce tanh(g)*N2L2E directly
    const float sA    = isG ? 2.0f * N2L2E : 1.0f;
    const float oA    = isG ? -N2L2E : 0.0f;

    const float* __restrict__ Whh = L ? Whh1 : Whh0;
    const float* __restrict__ bih = L ? bih1 : bih0;
    const float* __restrict__ bhh = L ? bhh1 : bhh0;

    // near weights (k = j^i) and far weights (k = j^4^i), own row only
    float wn1[4], wf1[4], wn2[4], wf2[4];
#pragma unroll
    for (int i = 0; i < 4; ++i) {
        const int kn = j ^ i;
        const int kf = j ^ 4 ^ i;
        wn1[i] = Whh[r * 8 + kn] * ws;
        wf1[i] = Whh[r * 8 + kf] * ws;
        wn2[i] = L ? Wlin[kn] : Wih1[r * 8 + kn] * ws;
        wf2[i] = L ? Wlin[kf] : Wih1[r * 8 + kf] * ws;
    }
    const float bias = (bih[r] + bhh[r]) * ws;
    const float wx   = L ? 0.0f : Wih0[r] * ws;
    const float b2   = L ? blin[0] : 0.0f;
    const float mL   = L ? 1.0f : 0.0f;
    const float keep = 1.0f - mL;
    const int  xaddr = (lane ^ 32) * 4;   // bpermute: cross layer halves

    const float* __restrict__ xp = x + (size_t)seq * Tsz;
    float* __restrict__ op       = out + (size_t)seq * Tsz;
    const bool storeLane = (lane == 32);

    float hn0 = 0.0f, hn1 = 0.0f, hn2 = 0.0f, hn3 = 0.0f;   // h(m-1) near
    float hf0 = 0.0f, hf1 = 0.0f, hf2 = 0.0f, hf3 = 0.0f;   // h(m-1) far
    float cs = 0.0f;          // c' = c * N2L2E (scale-folded cell state)
    float recvP = 0.0f;       // bperm result in flight (1-body slack)

    auto body = [&](float xt, bool fill, float* storePtr) {
        // -- top: cross-layer input from 2 bodies ago (bperm full slack)
        const float rB = recvP;
        const float t0 = fmaf(mL, rB, fmaf(wx, xt, bias));

        // -- near halves first (hn only: maximizes swz16->hf cover)
        float a1 = fmaf(wn1[0], hn0, t0);
        a1 = fmaf(wn1[1], hn1, a1);
        a1 = fmaf(wn1[2], hn2, a1);
        a1 = fmaf(wn1[3], hn3, a1);
        float a2 = fmaf(wn2[0], hn0, b2);
        a2 = fmaf(wn2[1], hn1, a2);
        a2 = fmaf(wn2[2], hn2, a2);
        a2 = fmaf(wn2[3], hn3, a2);

        // -- far halves (hf from tail-of-previous-body swz16)
        float f1 = wf1[0] * hf0;
        f1 = fmaf(wf1[1], hf1, f1);
        f1 = fmaf(wf1[2], hf2, f1);
        f1 = fmaf(wf1[3], hf3, f1);
        const float z = a1 + f1;

        float f2 = wf2[0] * hf0;
        f2 = fmaf(wf2[1], hf1, f2);
        f2 = fmaf(wf2[2], hf2, f2);
        f2 = fmaf(wf2[3], hf3, f2);
        const float d2 = a2 + f2;          // spare dot of h(m-1)
        if (storePtr && storeLane) *storePtr = d2;   // proj(h2(m-3))
        recvP = bperm(xaddr, d2);          // consumed next body

        // -- activation (pre-scaled): sig, or tanh*N2L2E for g~ lanes
        float a = fmaf(sA,
                       __builtin_amdgcn_rcpf(1.0f + __builtin_amdgcn_exp2f(z)),
                       oA);
        const float gi = dpp<0x00>(a);
        const float gf = dpp<0x55>(a);
        const float gG = dpp<0xAA>(a);        // = tanh(g)*N2L2E (pre-scaled)
        const float go = dpp<0xFF>(a);
        const float go2 = go + go;            // off-critical
        cs = fmaf(gf, cs, gi * gG);           // c' = c*N2L2E
        const float e  = __builtin_amdgcn_exp2f(cs);
        const float rr = __builtin_amdgcn_rcpf(1.0f + e);
        float h = fmaf(go2, rr, -go);         // = go*(2*rr-1)

        if (fill) { h *= keep; cs *= keep; }  // keep L1 state at zero

        // -- gather near h (intra-row DPP), then ship far h via swz16
        const float m7  = dpp<0x141>(h);     // ^7
        const float m15 = dpp<0x140>(h);     // ^15
        hn0 = h;                             // j
        hn1 = dpp<0x1B>(m7);                 // ^7^3  = ^4  -> j^1
        hn2 = dpp<0x141>(m15);               // ^15^7 = ^8  -> j^2
        hn3 = dpp<0x1B>(m15);                // ^15^3 = ^12 -> j^3
        hf0 = swz16(hn0);                    // j^4   (consumed next body)
        hf1 = swz16(hn1);                    // j^5
        hf2 = swz16(hn2);                    // j^6
        hf3 = swz16(hn3);                    // j^7
    };

    // ---- prologue: bodies 0,1 zero L1 state; body 2 = L1 step 0, no store
    body(xp[0], true, nullptr);
    body(xp[1], true, nullptr);
    body(xp[2], false, nullptr);

    // ---- steady, unrolled x4: m = 3 .. Tsz+2, store op[m-3]
    float xc[4];
#pragma unroll
    for (int u = 0; u < 4; ++u) xc[u] = xp[3 + u];   // x(3..6)
    for (int ck = 0; ck < Tsz / 4; ++ck) {
        const int base = 3 + 4 * ck;
        float xf[4];
#pragma unroll
        for (int u = 0; u < 4; ++u) {
            int idx = base + 4 + u;
            idx = (idx < Tsz) ? idx : (Tsz - 1);
            xf[u] = xp[idx];                 // prefetch next chunk (clamped)
        }
#pragma unroll
        for (int u = 0; u < 4; ++u)
            body(xc[u], false, op + (4 * ck + u));   // op[m-3]
#pragma unroll
        for (int u = 0; u < 4; ++u) xc[u] = xf[u];
    }
}

extern "C" void kernel_launch(void* const* d_in, const int* in_sizes, int n_in,
                              void* d_out, int out_size, void* d_ws, size_t ws_size,
                              hipStream_t stream) {
    const float* x    = (const float*)d_in[0];
    const float* Wih0 = (const float*)d_in[1];
    const float* Whh0 = (const float*)d_in[2];
    const float* bih0 = (const float*)d_in[3];
    const float* bhh0 = (const float*)d_in[4];
    const float* Wih1 = (const float*)d_in[5];
    const float* Whh1 = (const float*)d_in[6];
    const float* bih1 = (const float*)d_in[7];
    const float* bhh1 = (const float*)d_in[8];
    const float* Wlin = (const float*)d_in[9];
    const float* blin = (const float*)d_in[10];
    float* out = (float*)d_out;

    dim3 grid(Bsz / 4);   // 4 waves/block, 1 seq/wave -> 512 blocks, 2048 waves
    dim3 block(256);
    hipLaunchKernelGGL(lstm2_fl, grid, block, 0, stream,
                       x, Wih0, Whh0, bih0, bhh0,
                       Wih1, Whh1, bih1, bhh1, Wlin, blin, out);
}